// Round 1
// 1834.516 us; speedup vs baseline: 1.0655x; 1.0655x over previous
//
#include <hip/hip_runtime.h>

#define VIEWS 360
#define NDET 736
#define NX 512
#define NY 512
#define NPIX (NX * NY)

typedef unsigned short u16;
typedef __attribute__((ext_vector_type(8))) short bf16x8;
typedef __attribute__((ext_vector_type(4))) float f32x4;

__device__ __forceinline__ u16 f2bf(float f) {
  unsigned u = __float_as_uint(f);
  return (u16)((u + 0x7fffu + ((u >> 16) & 1u)) >> 16);
}

// ---------------------------------------------------------------------------
// Linear layer: out[v,d] = relu(b[d] + sum_k in[v,k] * w[d,k])
// ---------------------------------------------------------------------------
__global__ __launch_bounds__(256) void linear_relu_kernel(
    const float* __restrict__ in, const float* __restrict__ w,
    const float* __restrict__ b, float* __restrict__ out) {
  __shared__ __align__(16) float xin[NDET];
  const int v = blockIdx.x;
  const float4* src4 = (const float4*)(in + v * NDET);
  float4* dst4 = (float4*)xin;
  for (int k = threadIdx.x; k < NDET / 4; k += 256) dst4[k] = src4[k];
  __syncthreads();

  for (int d = threadIdx.x; d < NDET; d += 256) {
    const float4* w4 = (const float4*)(w + d * NDET);
    float acc = 0.f;
#pragma unroll 8
    for (int k = 0; k < NDET / 4; ++k) {
      float4 xv = ((const float4*)xin)[k];
      float4 wv = w4[k];
      acc = fmaf(xv.x, wv.x, acc);
      acc = fmaf(xv.y, wv.y, acc);
      acc = fmaf(xv.z, wv.z, acc);
      acc = fmaf(xv.w, wv.w, acc);
    }
    out[v * NDET + d] = fmaxf(acc + b[d], 0.f);
  }
}

// ---------------------------------------------------------------------------
// Backprojection v3: thread-owns-pixel (wave gathers = same view, consecutive
// pixels -> few cache lines, L1-hot sino) + idx reads coalesced via LDS
// staging of 72-view chunks. Row pad 77 dwords (77 mod 32 = 13, coprime) ->
// conflict-free LDS reads. 78.8 KB LDS -> 2 blocks/CU.
// ---------------------------------------------------------------------------
__global__ __launch_bounds__(256) void backproj_kernel(
    const float* __restrict__ sino, const int* __restrict__ idx,
    float* __restrict__ img) {
  __shared__ int lidx[256 * 77];
  const int t = threadIdx.x;
  const int p_base = blockIdx.x * 256;

  float a0 = 0.f, a1 = 0.f, a2 = 0.f, a3 = 0.f;

#pragma unroll 1
  for (int c = 0; c < 5; ++c) {
    if (c) __syncthreads();
    // stage: 256 rows x 72 views, int4-coalesced from global
#pragma unroll
    for (int k = 0; k < 18; ++k) {
      const int f = k * 256 + t;
      const int row = f / 18, col4 = f % 18;
      int4 v = *(const int4*)&idx[(size_t)(p_base + row) * VIEWS + c * 72 +
                                  col4 * 4];
      int* dst = &lidx[row * 77 + col4 * 4];
      dst[0] = v.x; dst[1] = v.y; dst[2] = v.z; dst[3] = v.w;
    }
    __syncthreads();
    const int* myrow = &lidx[t * 77];
#pragma unroll
    for (int j = 0; j < 72; j += 4) {
      a0 += sino[myrow[j + 0]];
      a1 += sino[myrow[j + 1]];
      a2 += sino[myrow[j + 2]];
      a3 += sino[myrow[j + 3]];
    }
  }

  const int p = p_base + t;
  const int ix = p >> 9, iy = p & 511;
  img[(NX - 1 - ix) * NY + (NY - 1 - iy)] =
      ((a0 + a1) + (a2 + a3)) * 0.00872665f;  // END_ANGLE / (2*VIEWS)
}

// ---------------------------------------------------------------------------
// fp32 3x3 neighborhood load (zero pad), single plane
// ---------------------------------------------------------------------------
__device__ __forceinline__ void load9(const float* __restrict__ base, int gx,
                                      int gy, float v[9]) {
  const bool xm = gx > 0, xp = gx < NX - 1, ym = gy > 0, yp = gy < NY - 1;
  const float* c = base + gy * NX + gx;
  v[0] = (ym && xm) ? c[-NX - 1] : 0.f;
  v[1] = (ym)       ? c[-NX]     : 0.f;
  v[2] = (ym && xp) ? c[-NX + 1] : 0.f;
  v[3] = (xm)       ? c[-1]      : 0.f;
  v[4] =               c[0];
  v[5] = (xp)       ? c[1]       : 0.f;
  v[6] = (yp && xm) ? c[NX - 1]  : 0.f;
  v[7] = (yp)       ? c[NX]      : 0.f;
  v[8] = (yp && xp) ? c[NX + 1]  : 0.f;
}

__device__ __forceinline__ float dot9(float a, const float v[9],
                                      const float* __restrict__ w) {
  a = fmaf(v[0], w[0], a);
  a = fmaf(v[1], w[1], a);
  a = fmaf(v[2], w[2], a);
  a = fmaf(v[3], w[3], a);
  a = fmaf(v[4], w[4], a);
  a = fmaf(v[5], w[5], a);
  a = fmaf(v[6], w[6], a);
  a = fmaf(v[7], w[7], a);
  a = fmaf(v[8], w[8], a);
  return a;
}

// ---------------------------------------------------------------------------
// conv_in: 1 -> 64 channels, fp32 plane in -> fp32 NHWC out, float4 stores.
// ---------------------------------------------------------------------------
__global__ __launch_bounds__(256) void conv_in_kernel(
    const float* __restrict__ in, const float* __restrict__ w,
    const float* __restrict__ b, float* __restrict__ out) {
  const int p = blockIdx.x * 256 + threadIdx.x;
  const int gx = p & (NX - 1), gy = p >> 9;
  float v[9];
  load9(in, gx, gy, v);
  float4* o = (float4*)(out + (size_t)p * 64);
#pragma unroll
  for (int oq = 0; oq < 16; ++oq) {
    float4 r;
    r.x = fmaxf(dot9(b[oq * 4 + 0], v, w + (oq * 4 + 0) * 9), 0.f);
    r.y = fmaxf(dot9(b[oq * 4 + 1], v, w + (oq * 4 + 1) * 9), 0.f);
    r.z = fmaxf(dot9(b[oq * 4 + 2], v, w + (oq * 4 + 2) * 9), 0.f);
    r.w = fmaxf(dot9(b[oq * 4 + 3], v, w + (oq * 4 + 3) * 9), 0.f);
    o[oq] = r;
  }
}

// ---------------------------------------------------------------------------
// Weight prep -> per-step wave-contiguous layout, kb-MAJOR step order:
//   s = kb*9 + tap  (was tap*2+kb) so conv64 can stage 32-ch halves.
// wR[li][s][lane=kg*16+n][mf][j] = W[li][oc=mf*16+n][ic=kb*32+kg*8+j][tap]
// ---------------------------------------------------------------------------
__global__ __launch_bounds__(256) void prep_weights_kernel(
    const float* __restrict__ bw1, const float* __restrict__ bw2,
    u16* __restrict__ wR) {
  const int g = blockIdx.x * 256 + threadIdx.x;
  if (g >= 22 * 36864) return;
  const int li = g / 36864, r1 = g % 36864;
  const int s = r1 / 2048, r2 = r1 % 2048;
  const int lane = r2 / 32, r3 = r2 % 32;
  const int mf = r3 / 8, j = r3 % 8;
  const int kb = s / 9, tap = s % 9;  // kb-major step order
  const int kg = lane >> 4, n = lane & 15;
  const int oc = mf * 16 + n;
  const int ic = kb * 32 + kg * 8 + j;
  const float* src = (li < 11) ? bw1 + li * 36864 : bw2 + (li - 11) * 36864;
  wR[g] = f2bf(src[(oc * 64 + ic) * 9 + tap]);
}

// ---------------------------------------------------------------------------
// conv64 MFMA implicit GEMM, NHWC. M=64 oc, N=64x*4y, K=576.
// K-SPLIT staging: LDS holds one 32-ch half [r=6][xi=66][4 chunks of 8ch]
// = 25.3 KB -> VGPR-capped 4 blocks/CU (launch_bounds 256,4). Grid 1024 =
// exactly 4 blocks/CU -> single fully-resident round, no tail.
// Step order kb-major (s = kb*9+tap), matching prep_weights_kernel.
// Swizzle: row = 4 slots x 16B = 64 B (half bank wrap) ->
//   slot = chunk ^ ((xi>>1)&3); bank group = (xi&1)*4 + slot -> 2 lanes per
//   4-bank group per 16-lane phase on both ds_write_b128 and ds_read_b128
//   (2-way = free).
// A fragments re-loaded from L2-hot wA each step (72 KB broadcast); tap loop
// unroll-3 lets the compiler hoist the 12 A-loads per group.
// mfma_f32_16x16x32_bf16; C/D col=lane&15, row=(lane>>4)*4+reg (m89-verified).
// ---------------------------------------------------------------------------
template <int IN_BF, int OUT_BF, int RELU, int ADDRES>
__global__ __launch_bounds__(256, 4) void conv64_mfma(
    const void* __restrict__ in_, const u16* __restrict__ wA,
    const float* __restrict__ bias, const float* __restrict__ res,
    void* __restrict__ out_) {
  __shared__ __align__(16) u16 lds[6 * 66 * 32];  // 25,344 B
  const int xb = (blockIdx.x & 7) * 64;
  const int yb = (int)(blockIdx.x >> 3) * 4;
  const int tid = threadIdx.x;
  const int wv = tid >> 6;
  const int lane = tid & 63;
  const int n = lane & 15;
  const int kg = lane >> 4;

  f32x4 acc[4][4];
#pragma unroll
  for (int i = 0; i < 4; ++i)
#pragma unroll
    for (int j = 0; j < 4; ++j) acc[i][j] = (f32x4){0.f, 0.f, 0.f, 0.f};

#pragma unroll 1
  for (int kb = 0; kb < 2; ++kb) {
    if (kb) __syncthreads();  // drain reads of previous half before overwrite
    // stage one 32-ch half: 6 rows x 66 xi x 4 chunks = 1584 uint4
#pragma unroll
    for (int it = 0; it < 7; ++it) {
      const int g = it * 256 + tid;
      if (g < 1584) {
        const int icq = g & 3;        // 8-ch chunk within this half
        const int xr = g >> 2;        // 0..395 = r*66 + x66
        const int x66 = xr % 66;
        const int r = xr / 66;
        const int y = yb - 1 + r;
        const int x = xb - 1 + x66;
        uint4 d = {0u, 0u, 0u, 0u};
        if ((unsigned)y < 512u && (unsigned)x < 512u) {
          const size_t gi =
              ((size_t)((y << 9) + x)) * 64 + kb * 32 + icq * 8;
          if (IN_BF) {
            d = *(const uint4*)&((const u16*)in_)[gi];
          } else {
            const float* s = &((const float*)in_)[gi];
            float4 f0 = *(const float4*)s;
            float4 f1 = *(const float4*)(s + 4);
            d.x = (unsigned)f2bf(f0.x) | ((unsigned)f2bf(f0.y) << 16);
            d.y = (unsigned)f2bf(f0.z) | ((unsigned)f2bf(f0.w) << 16);
            d.z = (unsigned)f2bf(f1.x) | ((unsigned)f2bf(f1.y) << 16);
            d.w = (unsigned)f2bf(f1.z) | ((unsigned)f2bf(f1.w) << 16);
          }
        }
        const int slot = icq ^ ((x66 >> 1) & 3);
        *(uint4*)&lds[(xr * 4 + slot) * 8] = d;
      }
    }
    __syncthreads();

#pragma unroll 3
    for (int tap = 0; tap < 9; ++tap) {
      const int s = kb * 9 + tap;
      bf16x8 av[4];
#pragma unroll
      for (int mf = 0; mf < 4; ++mf)
        av[mf] = *(const bf16x8*)&wA[((size_t)s * 64 + lane) * 32 + mf * 8];

      const int r = wv + tap / 3;
      const int dxp1 = tap % 3;

      bf16x8 bfr[4];
#pragma unroll
      for (int nf = 0; nf < 4; ++nf) {
        const int xi = dxp1 + nf * 16 + n;
        const int slot = kg ^ ((xi >> 1) & 3);
        bfr[nf] = *(const bf16x8*)&lds[((r * 66 + xi) * 4 + slot) * 8];
      }
#pragma unroll
      for (int mf = 0; mf < 4; ++mf)
#pragma unroll
        for (int nf = 0; nf < 4; ++nf)
          acc[mf][nf] = __builtin_amdgcn_mfma_f32_16x16x32_bf16(
              av[mf], bfr[nf], acc[mf][nf], 0, 0, 0);
    }
  }

  const int y = yb + wv;
#pragma unroll
  for (int mf = 0; mf < 4; ++mf) {
    const float4 bv = *(const float4*)&bias[mf * 16 + kg * 4];
#pragma unroll
    for (int nf = 0; nf < 4; ++nf) {
      const int x = xb + nf * 16 + n;
      const size_t base = ((size_t)((y << 9) + x)) * 64 + mf * 16 + kg * 4;
      float v0 = acc[mf][nf][0] + bv.x;
      float v1 = acc[mf][nf][1] + bv.y;
      float v2 = acc[mf][nf][2] + bv.z;
      float v3 = acc[mf][nf][3] + bv.w;
      if (ADDRES) {
        float4 rr = *(const float4*)&res[base];
        v0 += rr.x; v1 += rr.y; v2 += rr.z; v3 += rr.w;
      }
      if (RELU) {
        v0 = fmaxf(v0, 0.f); v1 = fmaxf(v1, 0.f);
        v2 = fmaxf(v2, 0.f); v3 = fmaxf(v3, 0.f);
      }
      if (OUT_BF) {
        uint2 pk;
        pk.x = (unsigned)f2bf(v0) | ((unsigned)f2bf(v1) << 16);
        pk.y = (unsigned)f2bf(v2) | ((unsigned)f2bf(v3) << 16);
        *(uint2*)&((u16*)out_)[base] = pk;
      } else {
        *(float4*)&((float*)out_)[base] = (float4){v0, v1, v2, v3};
      }
    }
  }
}

// ---------------------------------------------------------------------------
// conv_out: 64 -> 1, fp32 NHWC in (float4 loads), fp32 plane out.
// ---------------------------------------------------------------------------
__global__ __launch_bounds__(256) void conv_out_kernel(
    const float* __restrict__ in, const float* __restrict__ w,
    const float* __restrict__ b, float* __restrict__ out) {
  const int p = blockIdx.x * 256 + threadIdx.x;
  const int gx = p & (NX - 1), gy = p >> 9;
  float a = b[0];
#pragma unroll
  for (int ty = 0; ty < 3; ++ty) {
#pragma unroll
    for (int tx = 0; tx < 3; ++tx) {
      const int yy = gy + ty - 1, xx = gx + tx - 1;
      if ((unsigned)yy < 512u && (unsigned)xx < 512u) {
        const float4* q = (const float4*)(in + ((size_t)((yy << 9) + xx)) * 64);
        const int tap = ty * 3 + tx;
#pragma unroll
        for (int i = 0; i < 16; ++i) {
          float4 d = q[i];
          a = fmaf(d.x, w[(i * 4 + 0) * 9 + tap], a);
          a = fmaf(d.y, w[(i * 4 + 1) * 9 + tap], a);
          a = fmaf(d.z, w[(i * 4 + 2) * 9 + tap], a);
          a = fmaf(d.w, w[(i * 4 + 3) * 9 + tap], a);
        }
      }
    }
  }
  out[p] = a;
}

// ---------------------------------------------------------------------------
extern "C" void kernel_launch(void* const* d_in, const int* in_sizes, int n_in,
                              void* d_out, int out_size, void* d_ws,
                              size_t ws_size, hipStream_t stream) {
  const float* x      = (const float*)d_in[0];
  const int*   indices= (const int*)d_in[1];
  const float* w1     = (const float*)d_in[2];
  const float* b1     = (const float*)d_in[3];
  const float* w2     = (const float*)d_in[4];
  const float* b2     = (const float*)d_in[5];
  const float* cin_w  = (const float*)d_in[6];
  const float* cin_b  = (const float*)d_in[7];
  const float* bw1    = (const float*)d_in[8];
  const float* bb1    = (const float*)d_in[9];
  const float* bw2    = (const float*)d_in[10];
  const float* bb2    = (const float*)d_in[11];
  const float* cout_w = (const float*)d_in[12];
  const float* cout_b = (const float*)d_in[13];

  float* ws   = (float*)d_ws;
  float* h1   = ws;                      // 360*736 f32
  float* h2   = h1 + VIEWS * NDET;       // 360*736 f32
  float* img  = h2 + VIEWS * NDET;       // NPIX f32 (plane)
  float* yf   = img + NPIX;              // 64*NPIX f32 NHWC (residual stream)
  u16*  zb    = (u16*)(yf + 64 * NPIX);  // 64*NPIX bf16 NHWC
  u16*  wAll  = zb + 64 * NPIX;          // 22*64*576 bf16 (step layout)

  prep_weights_kernel<<<(22 * 36864 + 255) / 256, 256, 0, stream>>>(bw1, bw2,
                                                                    wAll);
  linear_relu_kernel<<<VIEWS, 256, 0, stream>>>(x, w1, b1, h1);
  linear_relu_kernel<<<VIEWS, 256, 0, stream>>>(h1, w2, b2, h2);
  backproj_kernel<<<NPIX / 256, 256, 0, stream>>>(h2, indices, img);
  conv_in_kernel<<<NPIX / 256, 256, 0, stream>>>(img, cin_w, cin_b, yf);

  for (int i = 0; i < 11; ++i) {
    conv64_mfma<0, 1, 1, 0><<<1024, 256, 0, stream>>>(
        yf, wAll + i * 36864, bb1 + i * 64, nullptr, zb);
    conv64_mfma<1, 0, 1, 1><<<1024, 256, 0, stream>>>(
        zb, wAll + (11 + i) * 36864, bb2 + i * 64, yf, yf);
  }
  conv_out_kernel<<<NPIX / 256, 256, 0, stream>>>(yf, cout_w, cout_b,
                                                  (float*)d_out);
}